// Round 7
// baseline (513.204 us; speedup 1.0000x reference)
//
#include <hip/hip_runtime.h>
#include <hip/hip_bf16.h>
#include <stdint.h>

#define KNN 8
#define S_ 5
#define D_ 5
#define NDE 4
#define NDC 12
#define NDCP 13
#define NDD 16
#define NPOS 80
#define ACT 5
#define PERK 172
#define XROW 1376
#define FEAT 784
#define FEATP 800
#define KSTEPS 25
#define H1 512
#define NBLK 1024

typedef __bf16 bf16x8 __attribute__((ext_vector_type(8)));
typedef float f32x4 __attribute__((ext_vector_type(4)));

static __device__ __forceinline__ unsigned short f2bf(float f) {
    unsigned int u = __builtin_bit_cast(unsigned int, f);
    u += 0x7fff + ((u >> 16) & 1);   // round-to-nearest-even
    return (unsigned short)(u >> 16);
}
static __device__ __forceinline__ float fsgnsqrt(float t) {
    return copysignf(sqrtf(fabsf(t)), t);
}

// Device-scope grid barrier (guide §6 G16): release fence + agent atomic arrive,
// agent-scope acquire spin, invalidate fence. Counter zeroed host-side per launch.
static __device__ __forceinline__ void gbar(unsigned* cnt, unsigned target) {
    __syncthreads();                      // all block stores complete (vmcnt drained per wave)
    if (threadIdx.x == 0) {
        __threadfence();                  // writeback L2 (release)
        __hip_atomic_fetch_add(cnt, 1u, __ATOMIC_RELEASE, __HIP_MEMORY_SCOPE_AGENT);
        while (__hip_atomic_load(cnt, __ATOMIC_ACQUIRE, __HIP_MEMORY_SCOPE_AGENT) < target)
            __builtin_amdgcn_s_sleep(2);
        __threadfence();                  // invalidate stale lines (acquire)
    }
    __syncthreads();
}

#define LDF(p, kk) __builtin_bit_cast(bf16x8, *(const uint4*)((p) + (kk) * 32))

__global__ __launch_bounds__(256, 4) void k_all(
    const float* __restrict__ x, const float* __restrict__ Wg, const float* __restrict__ bg,
    const float* __restrict__ W1, const float* __restrict__ b1,
    const float* __restrict__ adv_uw, const float* __restrict__ adv_sw,
    const float* __restrict__ adv_ub, const float* __restrict__ adv_sb,
    const float* __restrict__ v_uw, const float* __restrict__ v_sw,
    const float* __restrict__ v_ub, const float* __restrict__ v_sb,
    const float* __restrict__ ei_a, const float* __restrict__ eo_a,
    const float* __restrict__ ei_v, const float* __restrict__ eo_v,
    unsigned short* __restrict__ w1bf, unsigned short* __restrict__ featbf,
    float* __restrict__ h, float* __restrict__ wv, float* __restrict__ biasv,
    float* __restrict__ out, unsigned* __restrict__ cnt, int nB)
{
    const int bid = blockIdx.x;
    const int tid = threadIdx.x;

    __shared__ float xrow[XROW];
    __shared__ float sWg[NDC * NDC];
    __shared__ float sbg[NDC];
    __shared__ int   snd[NPOS];
    __shared__ int   sfirst[NPOS];
    __shared__ int   smfirst[NPOS];
    __shared__ float scw[NPOS];
    __shared__ float sdis[NPOS];
    __shared__ int   sNB[NPOS][4];
    __shared__ float sM[NPOS * NDCP];
    // tbl (u32[1024]) and sH (f32[1040]) have disjoint live ranges -> share storage
    __shared__ __align__(16) char uShared[NPOS * NDCP * 4];
    unsigned* tbl = (unsigned*)uShared;
    float* sH = (float*)uShared;

    // ================= Phase F: feat (4 batches/block) + W1 convert + noisy =================
    if (tid < 100) {   // 1024 blocks x 100 ushort4 = 512*800 exactly
        int g = bid * 100 + tid;
        int idx0 = g * 4;
        int n = idx0 / FEATP, k = idx0 - n * FEATP;
        ushort4 o;
        if (k < FEAT) {   // 4-groups never straddle 784 (784%4==0)
            float4 v = *(const float4*)(W1 + (size_t)n * FEAT + k);
            o.x = f2bf(v.x); o.y = f2bf(v.y); o.z = f2bf(v.z); o.w = f2bf(v.w);
        } else { o.x = 0; o.y = 0; o.z = 0; o.w = 0; }
        *(ushort4*)(w1bf + idx0) = o;
    }
    if (bid == 0) {
        for (int n = tid; n < H1; n += 256) {
            float fia = fsgnsqrt(ei_a[n]);
            float fiv = fsgnsqrt(ei_v[n]);
            #pragma unroll
            for (int a = 0; a < ACT; a++)
                wv[a * H1 + n] = adv_uw[a * H1 + n] + adv_sw[a * H1 + n] * fsgnsqrt(eo_a[a]) * fia;
            wv[5 * H1 + n] = v_uw[n] + v_sw[n] * fsgnsqrt(eo_v[0]) * fiv;
        }
        if (tid < ACT) biasv[tid] = adv_ub[tid] + adv_sb[tid] * fsgnsqrt(eo_a[tid]);
        if (tid == ACT) biasv[5] = v_ub[0] + v_sb[0] * fsgnsqrt(eo_v[0]);
    }
    for (int i = tid; i < NDC * NDC; i += 256) sWg[i] = Wg[i];
    if (tid < NDC) sbg[tid] = bg[tid];

    #pragma unroll 1
    for (int j = 0; j < 4; j++) {
        int b = bid * 4 + j;
        __syncthreads();   // xrow/tbl reuse across batches
        {
            const float4* xp4 = (const float4*)(x + (size_t)b * XROW);
            float4* xr4 = (float4*)xrow;
            for (int i = tid; i < XROW / 4; i += 256) xr4[i] = xp4[i];
        }
        for (int i = tid; i < 1024; i += 256) tbl[i] = 127u;
        __syncthreads();

        if (tid < NPOS) {
            int nd = (int)xrow[(tid / 10) * PERK + 160 + (tid % 10)];
            snd[tid] = nd;
            atomicMin(&tbl[nd], (unsigned)tid);   // cnt bits 0 here -> pure first-idx min
        }
        __syncthreads();
        if (tid < NPOS) atomicAdd(&tbl[snd[tid]], 256u);   // multiplicity in bits 8+
        __syncthreads();

        // per-node scalars
        if (tid < NPOS) {
            const int i = tid;
            const int ndi = snd[i];
            const int kbase = (i / 10) * 10;
            int r = ndi >> 5, c = ndi & 31;
            int nb0 = (((r + 31) & 31) << 5) | c;
            int nb1 = (((r + 1) & 31) << 5) | c;
            int nb2 = (r << 5) | ((c + 31) & 31);
            int nb3 = (r << 5) | ((c + 1) & 31);
            unsigned v = tbl[ndi];
            int f = (int)(v & 0xFFu);
            int cntv = (int)(v >> 8);
            unsigned v0 = tbl[nb0], v1 = tbl[nb1], v2 = tbl[nb2], v3 = tbl[nb3];
            sNB[i][0] = (int)(v0 & 0xFFu);
            sNB[i][1] = (int)(v1 & 0xFFu);
            sNB[i][2] = (int)(v2 & 0xFFu);
            sNB[i][3] = (int)(v3 & 0xFFu);
            int adjd = (int)((v0 >> 8) + (v1 >> 8) + (v2 >> 8) + (v3 >> 8));
            int mf = 127;
            #pragma unroll
            for (int jj = 9; jj >= 0; jj--) {
                if (snd[kbase + jj] == ndi) mf = kbase + jj;
            }
            sfirst[i] = f;
            smfirst[i] = mf;
            float dis = rsqrtf(1.0f + ((f == i) ? (float)adjd : 0.0f));
            sdis[i] = dis;
            scw[i] = (float)cntv * dis;
        }
        // M = all_info @ Wg over 960 (i,d) items
        for (int p = tid; p < NPOS * NDC; p += 256) {
            int i = p / NDC, d = p - i * NDC;
            int off = (i / 10) * PERK + (i % 10) * NDD + NDE;
            float s = 0.f;
            #pragma unroll
            for (int c2 = 0; c2 < NDC; c2++) s += xrow[off + c2] * sWg[c2 * NDC + d];
            sM[i * NDCP + d] = s;
        }
        __syncthreads();   // tbl dead; sH writable

        for (int p = tid; p < NPOS * NDC; p += 256) {
            int t = p / NDC, d = p - t * NDC;
            float dt = sdis[t];
            float a = dt * dt * sM[t * NDCP + d];
            if (sfirst[t] == t) {
                #pragma unroll
                for (int X = 0; X < 4; X++) {
                    int sX = sNB[t][X];
                    if (sX < NPOS) a += scw[sX] * dt * sM[sX * NDCP + d];
                }
            }
            sH[t * NDCP + d] = fmaxf(a + sbg[d], 0.f);
        }
        __syncthreads();

        // gather: per k: [6x12 gnn][2 els][6x4 each]; pad 784->800
        unsigned short* fout = featbf + (size_t)b * FEATP;
        for (int idx = tid; idx < FEATP; idx += 256) {
            float val = 0.f;
            if (idx < FEAT) {
                int k = idx / 98, rr = idx % 98;
                if (rr < 72) {
                    int t = rr / 12, d = rr % 12;
                    val = sH[sfirst[k * 10 + t] * NDCP + d];
                } else if (rr < 74) {
                    val = xrow[k * PERK + 170 + (rr - 72)];
                } else {
                    int q = rr - 74;
                    int t = q >> 2, e = q & 3;
                    int m = smfirst[k * 10 + t] - k * 10;
                    val = xrow[k * PERK + m * NDD + e];
                }
            }
            fout[idx] = f2bf(val);
        }
    }
    gbar(&cnt[0], (unsigned)gridDim.x);

    // ================= Phase G: h = relu(feat @ W1^T + b1), 64x32 tile/block =================
    {
        int lane = tid & 63, w = tid >> 6;
        int wg = (bid & 7) * 128 + (bid >> 3);   // bm-chunked XCD swizzle (1024 = 8*128)
        int bm = (wg >> 4) * 64;
        int bn = (wg & 15) * 32;
        int wr = w >> 1, wc = w & 1;
        int l15 = lane & 15;
        int kb = (lane >> 4) * 8;

        const unsigned short* pa0 = featbf + (size_t)(bm + wr * 32 + l15) * FEATP + kb;
        const unsigned short* pa1 = pa0 + 16 * FEATP;
        const unsigned short* pb0 = w1bf + (size_t)(bn + wc * 16 + l15) * FEATP + kb;

        f32x4 c0 = {0, 0, 0, 0}, c1 = {0, 0, 0, 0};
        bf16x8 a0  = LDF(pa0, 0);
        bf16x8 a1  = LDF(pa1, 0);
        bf16x8 bb0 = LDF(pb0, 0);
        #pragma unroll
        for (int kk = 0; kk < KSTEPS - 1; kk++) {
            bf16x8 na0  = LDF(pa0, kk + 1);
            bf16x8 na1  = LDF(pa1, kk + 1);
            bf16x8 nbb0 = LDF(pb0, kk + 1);
            c0 = __builtin_amdgcn_mfma_f32_16x16x32_bf16(a0, bb0, c0, 0, 0, 0);
            c1 = __builtin_amdgcn_mfma_f32_16x16x32_bf16(a1, bb0, c1, 0, 0, 0);
            a0 = na0; a1 = na1; bb0 = nbb0;
        }
        c0 = __builtin_amdgcn_mfma_f32_16x16x32_bf16(a0, bb0, c0, 0, 0, 0);
        c1 = __builtin_amdgcn_mfma_f32_16x16x32_bf16(a1, bb0, c1, 0, 0, 0);

        // C/D: col = lane&15, row = (lane>>4)*4 + reg  [m89]
        int row0 = bm + wr * 32 + (lane >> 4) * 4;
        int col0 = bn + wc * 16 + l15;
        float bias0 = b1[col0];
        #pragma unroll
        for (int r = 0; r < 4; r++) {
            h[(size_t)(row0 + r) * H1 + col0]      = fmaxf(c0[r] + bias0, 0.f);
            h[(size_t)(row0 + 16 + r) * H1 + col0] = fmaxf(c1[r] + bias0, 0.f);
        }
    }
    gbar(&cnt[1], (unsigned)gridDim.x);

    // ================= Phase O: dueling head, one row per wave =================
    {
        int w = tid >> 6, lane = tid & 63;
        int row = bid * 4 + w;
        if (row < nB) {
            const float4* hb4 = (const float4*)(h + (size_t)row * H1 + lane * 8);
            float4 h0 = hb4[0], h1 = hb4[1];
            float acc[6];
            #pragma unroll
            for (int a = 0; a < 6; a++) {
                const float4* wp4 = (const float4*)(wv + a * H1 + lane * 8);
                float4 w0 = wp4[0], w1 = wp4[1];
                acc[a] = h0.x * w0.x + h0.y * w0.y + h0.z * w0.z + h0.w * w0.w
                       + h1.x * w1.x + h1.y * w1.y + h1.z * w1.z + h1.w * w1.w;
            }
            #pragma unroll
            for (int a = 0; a < 6; a++) {
                #pragma unroll
                for (int off = 32; off > 0; off >>= 1) acc[a] += __shfl_xor(acc[a], off, 64);
            }
            float adv[5], ssum = 0.f;
            #pragma unroll
            for (int a = 0; a < 5; a++) { adv[a] = acc[a] + biasv[a]; ssum += adv[a]; }
            float vv = acc[5] + biasv[5];
            if (lane < 5) out[(size_t)row * 5 + lane] = vv + adv[lane] - ssum * 0.2f;
        }
    }
}

extern "C" void kernel_launch(void* const* d_in, const int* in_sizes, int n_in,
                              void* d_out, int out_size, void* d_ws, size_t ws_size,
                              hipStream_t stream)
{
    const float* x      = (const float*)d_in[0];
    const float* Wg     = (const float*)d_in[1];
    const float* bg     = (const float*)d_in[2];
    const float* W1     = (const float*)d_in[3];
    const float* b1     = (const float*)d_in[4];
    const float* adv_uw = (const float*)d_in[5];
    const float* adv_sw = (const float*)d_in[6];
    const float* adv_ub = (const float*)d_in[7];
    const float* adv_sb = (const float*)d_in[8];
    const float* v_uw   = (const float*)d_in[9];
    const float* v_sw   = (const float*)d_in[10];
    const float* v_ub   = (const float*)d_in[11];
    const float* v_sb   = (const float*)d_in[12];
    const float* ei_a   = (const float*)d_in[13];
    const float* eo_a   = (const float*)d_in[14];
    const float* ei_v   = (const float*)d_in[15];
    const float* eo_v   = (const float*)d_in[16];

    int nB = in_sizes[0] / XROW;   // 4096

    char* ws = (char*)d_ws;
    size_t off_feat = (size_t)H1 * FEATP * 2;                       // 819200
    unsigned short* w1bf   = (unsigned short*)ws;
    unsigned short* featbf = (unsigned short*)(ws + off_feat);
    float* h    = (float*)(ws + off_feat + (size_t)nB * FEATP * 2);
    float* wv   = (float*)((char*)h + (size_t)nB * H1 * 4);
    float* biasv = wv + 6 * H1;
    unsigned* cnt = (unsigned*)(ws + (size_t)32 * 1024 * 1024);     // far from data, 0-init below
    float* out  = (float*)d_out;

    hipMemsetAsync(cnt, 0, 8, stream);
    hipLaunchKernelGGL(k_all, dim3(NBLK), dim3(256), 0, stream,
                       x, Wg, bg, W1, b1,
                       adv_uw, adv_sw, adv_ub, adv_sb, v_uw, v_sw, v_ub, v_sb,
                       ei_a, eo_a, ei_v, eo_v,
                       w1bf, featbf, h, wv, biasv, out, cnt, nB);
}

// Round 8
// 139.137 us; speedup vs baseline: 3.6885x; 3.6885x over previous
//
#include <hip/hip_runtime.h>
#include <hip/hip_bf16.h>
#include <stdint.h>

#define KNN 8
#define S_ 5
#define D_ 5
#define NDE 4
#define NDC 12
#define NDCP 13
#define NDD 16
#define NPOS 80
#define ACT 5
#define PERK 172
#define XROW 1376
#define FEAT 784
#define FEATP 800
#define KSTEPS 25
#define H1 512

typedef __bf16 bf16x8 __attribute__((ext_vector_type(8)));
typedef float f32x4 __attribute__((ext_vector_type(4)));

static __device__ __forceinline__ unsigned short f2bf(float f) {
    unsigned int u = __builtin_bit_cast(unsigned int, f);
    u += 0x7fff + ((u >> 16) & 1);   // round-to-nearest-even
    return (unsigned short)(u >> 16);
}
static __device__ __forceinline__ float fsgnsqrt(float t) {
    return copysignf(sqrtf(fabsf(t)), t);
}

// ---------------- K1 (fused): feat blocks [0,nB) | W1->bf16 blocks [nB,nB+800) | noisy block ----------------
__global__ __launch_bounds__(128) void k_pre(const float* __restrict__ x,
                                             const float* __restrict__ Wg,
                                             const float* __restrict__ bg,
                                             unsigned short* __restrict__ featbf,
                                             const float* __restrict__ W1,
                                             unsigned short* __restrict__ w1bf,
                                             const float* __restrict__ adv_uw,
                                             const float* __restrict__ adv_sw,
                                             const float* __restrict__ adv_ub,
                                             const float* __restrict__ adv_sb,
                                             const float* __restrict__ v_uw,
                                             const float* __restrict__ v_sw,
                                             const float* __restrict__ v_ub,
                                             const float* __restrict__ v_sb,
                                             const float* __restrict__ ei_a,
                                             const float* __restrict__ eo_a,
                                             const float* __restrict__ ei_v,
                                             const float* __restrict__ eo_v,
                                             float* __restrict__ wv,
                                             float* __restrict__ bias,
                                             int nB)
{
    const int bid = blockIdx.x;
    const int tid = threadIdx.x;

    if (bid >= nB) {
        int pb = bid - nB;
        if (pb < 800) {
            // W1 f32 -> bf16, K-pad 784->800; 4 elements per thread
            int idx0 = (pb * 128 + tid) * 4;
            int n = idx0 / FEATP, k = idx0 - n * FEATP;
            ushort4 o;
            if (k < FEAT) {   // groups never straddle the 784 boundary (784%4==0)
                float4 v = *(const float4*)(W1 + (size_t)n * FEAT + k);
                o.x = f2bf(v.x); o.y = f2bf(v.y); o.z = f2bf(v.z); o.w = f2bf(v.w);
            } else {
                o.x = o.y = o.z = o.w = 0;
            }
            *(ushort4*)(w1bf + idx0) = o;
        } else {
            // noisy-net effective weights
            for (int n = tid; n < H1; n += 128) {
                float fia = fsgnsqrt(ei_a[n]);
                float fiv = fsgnsqrt(ei_v[n]);
                #pragma unroll
                for (int a = 0; a < ACT; a++)
                    wv[a * H1 + n] = adv_uw[a * H1 + n] + adv_sw[a * H1 + n] * fsgnsqrt(eo_a[a]) * fia;
                wv[5 * H1 + n] = v_uw[n] + v_sw[n] * fsgnsqrt(eo_v[0]) * fiv;
            }
            if (tid < ACT) bias[tid] = adv_ub[tid] + adv_sb[tid] * fsgnsqrt(eo_a[tid]);
            if (tid == ACT) bias[5] = v_ub[0] + v_sb[0] * fsgnsqrt(eo_v[0]);
        }
        return;
    }

    // ---- feat role ----
    __shared__ float xrow[XROW];
    __shared__ float sWg[NDC * NDC];
    __shared__ float sbg[NDC];
    __shared__ int   snd[NPOS];
    __shared__ int   sfirst[NPOS];
    __shared__ int   smfirst[NPOS];
    __shared__ float scw[NPOS];           // cnt * dis (valid at first indices)
    __shared__ float sdis[NPOS];
    __shared__ int   sNB[NPOS][4];        // first idx of each grid-neighbor value (127=absent)
    __shared__ float sM[NPOS * NDCP];
    // tbl (u32[1024], live until c1) and sH (f32[1040], live from (d)) share storage:
    __shared__ __align__(16) char uShared[NPOS * NDCP * 4];
    unsigned int* tbl = (unsigned int*)uShared;
    float* sH = (float*)uShared;

    const float4* xp4 = (const float4*)(x + (size_t)bid * XROW);
    float4* xr4 = (float4*)xrow;
    #pragma unroll
    for (int i = tid; i < XROW / 4; i += 128) xr4[i] = xp4[i];
    for (int i = tid; i < NDC * NDC; i += 128) sWg[i] = Wg[i];
    if (tid < NDC) sbg[tid] = bg[tid];
    #pragma unroll
    for (int i = tid; i < 1024; i += 128) tbl[i] = 127u;
    __syncthreads();

    if (tid < NPOS) {
        int k = tid / 10, m = tid % 10;
        int nd = (int)xrow[k * PERK + 160 + m];
        snd[tid] = nd;
        atomicMin(&tbl[nd], (unsigned)tid);   // cnt bits are 0 in this phase -> pure min on first
    }
    __syncthreads();
    if (tid < NPOS) atomicAdd(&tbl[snd[tid]], 256u);   // cnt in bits 8+
    __syncthreads();

    // c1: per-node scalars (80 threads)
    if (tid < NPOS) {
        const int i = tid;
        const int ndi = snd[i];
        const int kbase = (i / 10) * 10;
        int r = ndi >> 5, c = ndi & 31;
        int nb0 = (((r + 31) & 31) << 5) | c;
        int nb1 = (((r + 1) & 31) << 5) | c;
        int nb2 = (r << 5) | ((c + 31) & 31);
        int nb3 = (r << 5) | ((c + 1) & 31);
        unsigned v = tbl[ndi];
        int f = (int)(v & 0xFFu);
        int cnt = (int)(v >> 8);
        unsigned v0 = tbl[nb0], v1 = tbl[nb1], v2 = tbl[nb2], v3 = tbl[nb3];
        sNB[i][0] = (int)(v0 & 0xFFu);
        sNB[i][1] = (int)(v1 & 0xFFu);
        sNB[i][2] = (int)(v2 & 0xFFu);
        sNB[i][3] = (int)(v3 & 0xFFu);
        int adjd = (int)((v0 >> 8) + (v1 >> 8) + (v2 >> 8) + (v3 >> 8));
        int mf = 127;
        #pragma unroll
        for (int jj = 9; jj >= 0; jj--) {
            if (snd[kbase + jj] == ndi) mf = kbase + jj;
        }
        sfirst[i] = f;
        smfirst[i] = mf;
        float dis = rsqrtf(1.0f + ((f == i) ? (float)adjd : 0.0f));
        sdis[i] = dis;
        scw[i] = (float)cnt * dis;
    }
    // c2: M = all_info @ Wg, 960 (i,d) items over all 128 threads
    for (int p = tid; p < NPOS * NDC; p += 128) {
        int i = p / NDC, d = p - i * NDC;
        int off = (i / 10) * PERK + (i % 10) * NDD + NDE;
        float s = 0.f;
        #pragma unroll
        for (int c2 = 0; c2 < NDC; c2++) s += xrow[off + c2] * sWg[c2 * NDC + d];
        sM[i * NDCP + d] = s;
    }
    __syncthreads();   // tbl dead beyond this point; sH may now be written

    // d: H[t,d] = relu( dis_t^2*M[t,d] + is_first[t]*dis_t*sum_X scw[sX]*M[sX,d] + bg[d] )
    for (int p = tid; p < NPOS * NDC; p += 128) {
        int t = p / NDC, d = p - t * NDC;
        float dt = sdis[t];
        float a = dt * dt * sM[t * NDCP + d];
        if (sfirst[t] == t) {
            #pragma unroll
            for (int X = 0; X < 4; X++) {
                int sX = sNB[t][X];
                if (sX < NPOS) a += scw[sX] * dt * sM[sX * NDCP + d];
            }
        }
        sH[t * NDCP + d] = fmaxf(a + sbg[d], 0.f);
    }
    __syncthreads();

    // gather: per k: [6x12 gnn][2 els][6x4 each]; pad 784->800 with zeros
    unsigned short* fout = featbf + (size_t)bid * FEATP;
    for (int idx = tid; idx < FEATP; idx += 128) {
        float val = 0.f;
        if (idx < FEAT) {
            int k = idx / 98, rr = idx % 98;
            if (rr < 72) {
                int t = rr / 12, d = rr % 12;
                val = sH[sfirst[k * 10 + t] * NDCP + d];
            } else if (rr < 74) {
                val = xrow[k * PERK + 170 + (rr - 72)];
            } else {
                int q = rr - 74;
                int t = q >> 2, e = q & 3;
                int m = smfirst[k * 10 + t] - k * 10;
                val = xrow[k * PERK + m * NDD + e];
            }
        }
        fout[idx] = f2bf(val);
    }
}

// ---------------- K2: fused GEMM + dueling head. One block = 16 rows x all 512 cols ----------------
#define LDF(p, kk) __builtin_bit_cast(bf16x8, *(const uint4*)((p) + (kk) * 32))

__global__ __launch_bounds__(512) void k_gh(const unsigned short* __restrict__ A,
                                            const unsigned short* __restrict__ Bw,
                                            const float* __restrict__ b1,
                                            const float* __restrict__ wv,
                                            const float* __restrict__ biasv,
                                            float* __restrict__ out, int nB)
{
    __shared__ float swv[6 * H1];          // noisy weights, 12 KB
    __shared__ float spart[8][16][6];      // per-wave row/action partials, 3 KB

    const int tid = threadIdx.x;
    const int lane = tid & 63;
    const int w = tid >> 6;                // 8 waves
    const int bm = blockIdx.x * 16;        // 16 batch rows per block
    const int bn = w * 64;                 // each wave: 64 output cols
    const int l15 = lane & 15;
    const int kb = (lane >> 4) * 8;

    for (int i = tid; i < 6 * H1; i += 512) swv[i] = wv[i];

    const unsigned short* pa = A + (size_t)(bm + l15) * FEATP + kb;
    const unsigned short* pb0 = Bw + (size_t)(bn + l15) * FEATP + kb;
    const unsigned short* pb1 = pb0 + 16 * FEATP;
    const unsigned short* pb2 = pb0 + 32 * FEATP;
    const unsigned short* pb3 = pb0 + 48 * FEATP;

    f32x4 c0 = {0,0,0,0}, c1 = {0,0,0,0}, c2 = {0,0,0,0}, c3 = {0,0,0,0};

    bf16x8 av = LDF(pa, 0);
    bf16x8 b0 = LDF(pb0, 0), b1v = LDF(pb1, 0), b2 = LDF(pb2, 0), b3 = LDF(pb3, 0);
    #pragma unroll
    for (int kk = 0; kk < KSTEPS - 1; kk++) {
        bf16x8 nav = LDF(pa, kk + 1);
        bf16x8 nb0 = LDF(pb0, kk + 1), nb1 = LDF(pb1, kk + 1);
        bf16x8 nb2 = LDF(pb2, kk + 1), nb3 = LDF(pb3, kk + 1);
        c0 = __builtin_amdgcn_mfma_f32_16x16x32_bf16(av, b0, c0, 0, 0, 0);
        c1 = __builtin_amdgcn_mfma_f32_16x16x32_bf16(av, b1v, c1, 0, 0, 0);
        c2 = __builtin_amdgcn_mfma_f32_16x16x32_bf16(av, b2, c2, 0, 0, 0);
        c3 = __builtin_amdgcn_mfma_f32_16x16x32_bf16(av, b3, c3, 0, 0, 0);
        av = nav; b0 = nb0; b1v = nb1; b2 = nb2; b3 = nb3;
    }
    c0 = __builtin_amdgcn_mfma_f32_16x16x32_bf16(av, b0, c0, 0, 0, 0);
    c1 = __builtin_amdgcn_mfma_f32_16x16x32_bf16(av, b1v, c1, 0, 0, 0);
    c2 = __builtin_amdgcn_mfma_f32_16x16x32_bf16(av, b2, c2, 0, 0, 0);
    c3 = __builtin_amdgcn_mfma_f32_16x16x32_bf16(av, b3, c3, 0, 0, 0);

    // C/D layout [m89]: local row = (lane>>4)*4 + r, col_n = bn + n*16 + l15
    int col0 = bn + l15;
    float bb0 = b1[col0], bb1 = b1[col0 + 16], bb2 = b1[col0 + 32], bb3 = b1[col0 + 48];
    float h0[4], h1[4], h2[4], h3[4];
    #pragma unroll
    for (int r = 0; r < 4; r++) {
        h0[r] = fmaxf(c0[r] + bb0, 0.f);
        h1[r] = fmaxf(c1[r] + bb1, 0.f);
        h2[r] = fmaxf(c2[r] + bb2, 0.f);
        h3[r] = fmaxf(c3[r] + bb3, 0.f);
    }
    __syncthreads();   // swv ready (also spart safe)

    // head partials: per (a, r): p = sum_n h_n[r]*swv[a][col_n]; 16-lane xor-reduce; lane l15==0 stores
    #pragma unroll
    for (int a = 0; a < 6; a++) {
        float w0 = swv[a * H1 + col0];
        float w1 = swv[a * H1 + col0 + 16];
        float w2 = swv[a * H1 + col0 + 32];
        float w3 = swv[a * H1 + col0 + 48];
        #pragma unroll
        for (int r = 0; r < 4; r++) {
            float p = h0[r] * w0 + h1[r] * w1 + h2[r] * w2 + h3[r] * w3;
            p += __shfl_xor(p, 1, 64);
            p += __shfl_xor(p, 2, 64);
            p += __shfl_xor(p, 4, 64);
            p += __shfl_xor(p, 8, 64);
            if (l15 == 0) spart[w][(lane >> 4) * 4 + r][a] = p;
        }
    }
    __syncthreads();

    // combine 8 waves + dueling, one thread per row
    if (tid < 16) {
        float acc[6];
        #pragma unroll
        for (int a = 0; a < 6; a++) {
            float s = 0.f;
            #pragma unroll
            for (int ww = 0; ww < 8; ww++) s += spart[ww][tid][a];
            acc[a] = s;
        }
        float adv[5], ssum = 0.f;
        #pragma unroll
        for (int a = 0; a < 5; a++) { adv[a] = acc[a] + biasv[a]; ssum += adv[a]; }
        float vv = acc[5] + biasv[5];
        int row = bm + tid;
        #pragma unroll
        for (int a = 0; a < 5; a++) out[(size_t)row * 5 + a] = vv + adv[a] - ssum * 0.2f;
    }
}

extern "C" void kernel_launch(void* const* d_in, const int* in_sizes, int n_in,
                              void* d_out, int out_size, void* d_ws, size_t ws_size,
                              hipStream_t stream)
{
    const float* x      = (const float*)d_in[0];
    const float* Wg     = (const float*)d_in[1];
    const float* bg     = (const float*)d_in[2];
    const float* W1     = (const float*)d_in[3];
    const float* b1     = (const float*)d_in[4];
    const float* adv_uw = (const float*)d_in[5];
    const float* adv_sw = (const float*)d_in[6];
    const float* adv_ub = (const float*)d_in[7];
    const float* adv_sb = (const float*)d_in[8];
    const float* v_uw   = (const float*)d_in[9];
    const float* v_sw   = (const float*)d_in[10];
    const float* v_ub   = (const float*)d_in[11];
    const float* v_sb   = (const float*)d_in[12];
    const float* ei_a   = (const float*)d_in[13];
    const float* eo_a   = (const float*)d_in[14];
    const float* ei_v   = (const float*)d_in[15];
    const float* eo_v   = (const float*)d_in[16];

    int nB = in_sizes[0] / XROW;   // 4096

    char* ws = (char*)d_ws;
    size_t off_feat = (size_t)H1 * FEATP * 2;                       // 819200
    unsigned short* w1bf   = (unsigned short*)ws;
    unsigned short* featbf = (unsigned short*)(ws + off_feat);
    float* wv   = (float*)(ws + off_feat + (size_t)nB * FEATP * 2);
    float* biasv = wv + 6 * H1;
    float* out  = (float*)d_out;

    // fused: nB feat blocks + 800 W1-convert blocks + 1 noisy block
    hipLaunchKernelGGL(k_pre, dim3(nB + 801), dim3(128), 0, stream,
                       x, Wg, bg, featbf, W1, w1bf,
                       adv_uw, adv_sw, adv_ub, adv_sb, v_uw, v_sw, v_ub, v_sb,
                       ei_a, eo_a, ei_v, eo_v, wv, biasv, nB);
    hipLaunchKernelGGL(k_gh, dim3(nB / 16), dim3(512), 0, stream,
                       featbf, w1bf, b1, wv, biasv, out, nB);
}